// Round 1
// baseline (215.101 us; speedup 1.0000x reference)
//
#include <hip/hip_runtime.h>
#include <math.h>

#define NPTS 262144
#define KC 512
#define DD 64

// Kernel 1: copy centroids to output 0 and compute c_sq (numpy pairwise-8 order).
__global__ __launch_bounds__(256) void prep_kernel(const float* __restrict__ c,
                                                   float* __restrict__ out_c,
                                                   float* __restrict__ c_sq) {
    int j = blockIdx.x * 256 + threadIdx.x;
    if (j < KC * DD) out_c[j] = c[j];
    if (j < KC) {
        const float* row = c + j * DD;
        float r[8];
#pragma unroll
        for (int t = 0; t < 8; ++t) r[t] = __fmul_rn(row[t], row[t]);
#pragma unroll
        for (int b = 1; b < 8; ++b) {
#pragma unroll
            for (int t = 0; t < 8; ++t)
                r[t] = __fadd_rn(r[t], __fmul_rn(row[8 * b + t], row[8 * b + t]));
        }
        c_sq[j] = __fadd_rn(__fadd_rn(__fadd_rn(r[0], r[1]), __fadd_rn(r[2], r[3])),
                            __fadd_rn(__fadd_rn(r[4], r[5]), __fadd_rn(r[6], r[7])));
    }
}

// Kernel 2: one thread per point. x row in VGPRs; centroids read wave-uniformly
// (k,d are uniform loop indices -> scalar loads); running argmin in registers.
__global__ __launch_bounds__(256) void assign_kernel(const float* __restrict__ x,
                                                     const float* __restrict__ c,
                                                     const float* __restrict__ c_sq,
                                                     float* __restrict__ out_assign) {
    int i = blockIdx.x * 256 + threadIdx.x;
    if (i >= NPTS) return;

    float xv[DD];
    const float4* xp = reinterpret_cast<const float4*>(x + (size_t)i * DD);
#pragma unroll
    for (int q = 0; q < DD / 4; ++q) {
        float4 v = xp[q];
        xv[4 * q + 0] = v.x;
        xv[4 * q + 1] = v.y;
        xv[4 * q + 2] = v.z;
        xv[4 * q + 3] = v.w;
    }

    // x_sq with numpy's pairwise-8 summation order (square rounded separately).
    float r[8];
#pragma unroll
    for (int t = 0; t < 8; ++t) r[t] = __fmul_rn(xv[t], xv[t]);
#pragma unroll
    for (int b = 1; b < 8; ++b) {
#pragma unroll
        for (int t = 0; t < 8; ++t)
            r[t] = __fadd_rn(r[t], __fmul_rn(xv[8 * b + t], xv[8 * b + t]));
    }
    float x_sq = __fadd_rn(__fadd_rn(__fadd_rn(r[0], r[1]), __fadd_rn(r[2], r[3])),
                           __fadd_rn(__fadd_rn(r[4], r[5]), __fadd_rn(r[6], r[7])));

    float best = INFINITY;
    int best_k = 0;
    for (int k = 0; k < KC; ++k) {
        const float* crow = c + (size_t)k * DD;
        float a0 = 0.f, a1 = 0.f, a2 = 0.f, a3 = 0.f;
#pragma unroll
        for (int d = 0; d < DD; d += 4) {
            a0 = __fmaf_rn(xv[d + 0], crow[d + 0], a0);
            a1 = __fmaf_rn(xv[d + 1], crow[d + 1], a1);
            a2 = __fmaf_rn(xv[d + 2], crow[d + 2], a2);
            a3 = __fmaf_rn(xv[d + 3], crow[d + 3], a3);
        }
        float acc = __fadd_rn(__fadd_rn(a0, a1), __fadd_rn(a2, a3));
        // Replicate reference: (x_sq + c_sq[k]) - 2.0*cross, each op rounded once.
        float t = __fadd_rn(x_sq, c_sq[k]);
        float dist = __fadd_rn(t, -2.0f * acc);  // -2*acc is exact
        if (dist < best) { best = dist; best_k = k; }  // strict <: first index wins
    }
    out_assign[i] = (float)best_k;
}

extern "C" void kernel_launch(void* const* d_in, const int* in_sizes, int n_in,
                              void* d_out, int out_size, void* d_ws, size_t ws_size,
                              hipStream_t stream) {
    const float* x = (const float*)d_in[0];
    const float* c = (const float*)d_in[1];
    float* out = (float*)d_out;
    float* c_sq = (float*)d_ws;

    prep_kernel<<<(KC * DD + 255) / 256, 256, 0, stream>>>(c, out, c_sq);
    assign_kernel<<<NPTS / 256, 256, 0, stream>>>(x, c, c_sq, out + KC * DD);
}